// Round 3
// baseline (1298.717 us; speedup 1.0000x reference)
//
#include <hip/hip_runtime.h>
#include <stdint.h>

#define NB 32
#define TDEC 1024
#define TSRC 2048
#define DDIM 1024

typedef short bf16x8 __attribute__((ext_vector_type(8)));
typedef float f32x4 __attribute__((ext_vector_type(4)));

// ---------- helpers ----------

__device__ __forceinline__ unsigned short f2bf(float f) {  // round-to-nearest bf16
  union { float f; uint32_t u; } c; c.f = f;
  return (unsigned short)((c.u + 0x7FFFu + ((c.u >> 16) & 1u)) >> 16);
}

// truncating split: f = hi + lo (+ residual ~2^-17 |f|)
__device__ __forceinline__ void splitt(float f, unsigned short& h, unsigned short& l) {
  union { float f; uint32_t u; } c; c.f = f;
  uint32_t hb = c.u & 0xFFFF0000u;
  h = (unsigned short)(hb >> 16);
  union { uint32_t u; float f; } hf; hf.u = hb;
  union { float f; uint32_t u; } d; d.f = f - hf.f;
  l = (unsigned short)(d.u >> 16);
}

// XOR-swizzled LDS index for a 128x64 bf16 tile stored with LDK=64 (no pad).
// LDS slot s of row r holds global k-granule s^(r&7) (8 bf16 per granule).
// This exact layout measured 0 bank conflicts (round-0/2 counters).
__device__ __forceinline__ int sw4(int r, int c4) {
  return (r << 6) + ((((c4 >> 3) ^ (r & 7)) << 3) | (c4 & 7));
}
__device__ __forceinline__ int sw8(int r, int c8) {
  return (r << 6) + (((c8 >> 3) ^ (r & 7)) << 3);
}

// async global->LDS, 16B per lane. LDS dest must be wave-uniform base + lane*16
// (linear); the swizzle is applied by PRE-SWIZZLING the per-lane global source
// address (rule 21 / m173 pattern; XOR swizzle is its own inverse).
__device__ __forceinline__ void gload16(const void* g, void* l) {
  __builtin_amdgcn_global_load_lds(
      reinterpret_cast<const __attribute__((address_space(1))) uint32_t*>(
          reinterpret_cast<uintptr_t>(g)),
      reinterpret_cast<__attribute__((address_space(3))) uint32_t*>(
          reinterpret_cast<uintptr_t>(l)),
      16, 0, 0);
}

// ---------- kernel 1: mask -> per-batch valid length ----------
__global__ void lens_kernel(const unsigned char* __restrict__ mask,
                            int* __restrict__ lens) {
  int b = blockIdx.x;
  int tid = threadIdx.x;
  unsigned char b1 = mask[1], b3 = mask[3];
  int cnt = 0;
  if (b1 != 0) {
    const unsigned char* row = mask + (size_t)b * TSRC;
    for (int s = tid; s < TSRC; s += 256) cnt += (row[s] != 0) ? 1 : 0;
  } else if (b3 != 0) {
    const float* row = (const float*)mask + (size_t)b * TSRC;
    for (int s = tid; s < TSRC; s += 256) cnt += (row[s] != 0.0f) ? 1 : 0;
  } else {
    const int* row = (const int*)mask + (size_t)b * TSRC;
    for (int s = tid; s < TSRC; s += 256) cnt += (row[s] != 0) ? 1 : 0;
  }
#pragma unroll
  for (int o = 32; o > 0; o >>= 1) cnt += __shfl_down(cnt, o, 64);
  __shared__ int red[4];
  if ((tid & 63) == 0) red[tid >> 6] = cnt;
  __syncthreads();
  if (tid == 0) lens[b] = red[0] + red[1] + red[2] + red[3];
}

// ---------- kernel 2: dec fp32 -> bf16 hi/lo split (flat) ----------
__global__ void split_kernel(const float* __restrict__ src,
                             unsigned short* __restrict__ hi,
                             unsigned short* __restrict__ lo, int n4) {
  int i = blockIdx.x * 256 + threadIdx.x;
  if (i >= n4) return;
  float4 v = *(const float4*)(src + (size_t)i * 4);
  ushort4 h, l;
  splitt(v.x, h.x, l.x); splitt(v.y, h.y, l.y);
  splitt(v.z, h.z, l.z); splitt(v.w, h.w, l.w);
  *(ushort4*)(hi + (size_t)i * 4) = h;
  *(ushort4*)(lo + (size_t)i * 4) = l;
}

// ---------- kernel 3: enc -> {enc_hi, enc_lo} [s][d] + encT [d][s] in ONE read ----------
__global__ void encprep_kernel(const float* __restrict__ enc,
                               unsigned short* __restrict__ ehi,
                               unsigned short* __restrict__ elo,
                               unsigned short* __restrict__ encT) {
  __shared__ float tile[64][65];  // +1 pad: conflict-free both phases
  int b = blockIdx.z;
  int s0 = blockIdx.x << 6;
  int d0 = blockIdx.y << 6;
  int tid = threadIdx.x;
  int rl = tid >> 4;             // 0..15
  int c4 = (tid & 15) << 2;      // 0..60
  const float* src = enc + ((size_t)b * TSRC + s0) * DDIM + d0;
  unsigned short* hdst = ehi + ((size_t)b * TSRC + s0) * DDIM + d0;
  unsigned short* ldst = elo + ((size_t)b * TSRC + s0) * DDIM + d0;
#pragma unroll
  for (int p = 0; p < 4; ++p) {
    int s = rl + (p << 4);
    float4 v = *(const float4*)(src + (size_t)s * DDIM + c4);
    tile[s][c4 + 0] = v.x; tile[s][c4 + 1] = v.y;
    tile[s][c4 + 2] = v.z; tile[s][c4 + 3] = v.w;
    ushort4 h, l;
    splitt(v.x, h.x, l.x); splitt(v.y, h.y, l.y);
    splitt(v.z, h.z, l.z); splitt(v.w, h.w, l.w);
    *(ushort4*)(hdst + (size_t)s * DDIM + c4) = h;
    *(ushort4*)(ldst + (size_t)s * DDIM + c4) = l;
  }
  __syncthreads();
  unsigned short* dst = encT + ((size_t)b * DDIM + d0) * TSRC + s0;
#pragma unroll
  for (int p = 0; p < 4; ++p) {
    int d = rl + (p << 4);
    ushort4 o;
    o.x = f2bf(tile[c4 + 0][d]);
    o.y = f2bf(tile[c4 + 1][d]);
    o.z = f2bf(tile[c4 + 2][d]);
    o.w = f2bf(tile[c4 + 3][d]);
    *(ushort4*)(dst + (size_t)d * TSRC + c4) = o;
  }
}

// ---------- kernel 4: scores via concat-K (K'=3072) 2-phase pipelined GEMM ----------
// dec@enc^T hi/lo 3-product split folded into the K axis:
//   seg0 (kc 0..15):  dec_hi . enc_hi
//   seg1 (kc 16..31): dec_lo . enc_hi
//   seg2 (kc 32..47): dec_hi . enc_lo
// Plain single-product bf16 GEMM -> only 2 LDS operand buffers -> double-buffer
// fits in 64 KB. Counted vmcnt(8) keeps next-tile loads in flight across the
// raw s_barrier (T3/T4); never drain vmcnt to 0 in the main loop.
__global__ __launch_bounds__(256, 2) void scores_pre(
    const unsigned short* __restrict__ dhi, const unsigned short* __restrict__ dlo,
    const unsigned short* __restrict__ ehi, const unsigned short* __restrict__ elo,
    float* __restrict__ attn, const int* __restrict__ lens) {
  int b = blockIdx.z;
  int s0 = blockIdx.x << 7;
  int t0 = blockIdx.y << 7;
  if (s0 >= lens[b]) return;  // fully-masked tile: softmax writes the zeros
  __shared__ __align__(16) unsigned short As[2][8192], Bs[2][8192];  // 64 KB
  const unsigned short* Ag0 = dhi + ((size_t)b * TDEC + t0) * DDIM;
  const unsigned short* Ag1 = dlo + ((size_t)b * TDEC + t0) * DDIM;
  const unsigned short* Bg0 = ehi + ((size_t)b * TSRC + s0) * DDIM;
  const unsigned short* Bg1 = elo + ((size_t)b * TSRC + s0) * DDIM;
  int tid = threadIdx.x;
  int lane = tid & 63, wid = tid >> 6;
  int wm = (wid >> 1) << 6, wn = (wid & 1) << 6;
  int fr = lane & 15, fq = lane >> 4;

  // staging geometry: granule g = p*256+tid; row r=g>>3; LDS slot g&7 receives
  // global granule (g&7)^(r&7). 4 granules/thread per operand per K-step.
  int gg[4]; size_t go[4];
#pragma unroll
  for (int p = 0; p < 4; ++p) {
    int g = (p << 8) + tid;
    int r = g >> 3;
    int sg = (g & 7) ^ (r & 7);
    gg[p] = g << 3;                       // LDS ushort offset (linear)
    go[p] = (size_t)r * DDIM + (sg << 3); // pre-swizzled global elem offset
  }

  f32x4 acc[16];
#pragma unroll
  for (int i = 0; i < 16; ++i) { acc[i][0] = 0.f; acc[i][1] = 0.f; acc[i][2] = 0.f; acc[i][3] = 0.f; }

  auto stage = [&](int buf, int kc) {
    // wave-uniform segment select (s_cselect, no pointer array -> no scratch)
    const unsigned short* Ab = (kc >= 16 && kc < 32) ? Ag1 : Ag0;
    const unsigned short* Bb = (kc >= 32) ? Bg1 : Bg0;
    int k0 = (kc & 15) << 6;
    unsigned short* Ad = &As[buf][0];
    unsigned short* Bd = &Bs[buf][0];
#pragma unroll
    for (int p = 0; p < 4; ++p) {
      gload16(Ab + go[p] + k0, Ad + gg[p]);
      gload16(Bb + go[p] + k0, Bd + gg[p]);
    }
  };

  auto compute = [&](int buf) {
    const unsigned short* At = &As[buf][0];
    const unsigned short* Bt = &Bs[buf][0];
#pragma unroll
    for (int ks = 0; ks < 2; ++ks) {
      bf16x8 a[4], bb[4];
#pragma unroll
      for (int i = 0; i < 4; ++i) {
        int ra = wm + (i << 4) + fr;
        a[i] = *(const bf16x8*)&At[(ra << 6) + ((((ks << 2) | fq) ^ (ra & 7)) << 3)];
        int rb = wn + (i << 4) + fr;
        bb[i] = *(const bf16x8*)&Bt[(rb << 6) + ((((ks << 2) | fq) ^ (rb & 7)) << 3)];
      }
#pragma unroll
      for (int mt = 0; mt < 4; ++mt)
#pragma unroll
        for (int nt = 0; nt < 4; ++nt)
          acc[(mt << 2) + nt] = __builtin_amdgcn_mfma_f32_16x16x32_bf16(
              a[mt], bb[nt], acc[(mt << 2) + nt], 0, 0, 0);
    }
  };

  // 2-phase pipeline over K' = 48 steps of 64.
  stage(0, 0);
  int cur = 0;
  for (int kc = 0; kc < 47; ++kc) {
    stage(cur ^ 1, kc + 1);                       // 8 more loads -> 16 in flight
    asm volatile("s_waitcnt vmcnt(8)" ::: "memory");  // oldest 8 (cur buf) done
    __builtin_amdgcn_s_barrier();                 // cur buf globally ready
    __builtin_amdgcn_sched_barrier(0);
    compute(cur);
    __builtin_amdgcn_sched_barrier(0);
    __builtin_amdgcn_s_barrier();                 // all waves done reading cur
    cur ^= 1;
  }
  asm volatile("s_waitcnt vmcnt(0)" ::: "memory");
  __builtin_amdgcn_s_barrier();
  __builtin_amdgcn_sched_barrier(0);
  compute(cur);

  // C/D layout (verified m89): col = lane&15, row = (lane>>4)*4 + reg
  float* C = attn + ((size_t)b * TDEC + t0) * TSRC + s0;
#pragma unroll
  for (int mt = 0; mt < 4; ++mt) {
    int r0 = wm + (mt << 4) + (fq << 2);
#pragma unroll
    for (int nt = 0; nt < 4; ++nt) {
      int c0 = wn + (nt << 4) + fr;
      f32x4 v = acc[(mt << 2) + nt];
#pragma unroll
      for (int j = 0; j < 4; ++j)
        C[(size_t)(r0 + j) * TSRC + c0] = v[j];
    }
  }
}

// ---------- scores fallback: on-the-fly split from fp32 (small-ws path) ----------
__global__ __launch_bounds__(256, 2) void scores_fly(
    const float* __restrict__ dec, const float* __restrict__ enc,
    float* __restrict__ attn, const int* __restrict__ lens) {
  int b = blockIdx.z;
  int s0 = blockIdx.x << 7;
  int t0 = blockIdx.y << 7;
  if (s0 >= lens[b]) return;
  __shared__ unsigned short Ah[8192], Al[8192], Bh[8192], Bl[8192];
  const float* Ag = dec + ((size_t)b * TDEC + t0) * DDIM;
  const float* Bg = enc + ((size_t)b * TSRC + s0) * DDIM;
  int tid = threadIdx.x;
  int lane = tid & 63, wid = tid >> 6;
  int wm = (wid >> 1) << 6, wn = (wid & 1) << 6;
  int fr = lane & 15, fq = lane >> 4;

  f32x4 acc[16];
#pragma unroll
  for (int i = 0; i < 16; ++i) { acc[i][0] = 0.f; acc[i][1] = 0.f; acc[i][2] = 0.f; acc[i][3] = 0.f; }

  for (int kc = 0; kc < 16; ++kc) {
    int k0 = kc << 6;
    __syncthreads();
#pragma unroll
    for (int p = 0; p < 8; ++p) {
      int r = (p << 4) + (tid >> 4);
      int c4 = (tid & 15) << 2;
      size_t go = (size_t)r * DDIM + k0 + c4;
      float4 va = *(const float4*)(Ag + go);
      float4 vb = *(const float4*)(Bg + go);
      ushort4 h, l;
      splitt(va.x, h.x, l.x); splitt(va.y, h.y, l.y);
      splitt(va.z, h.z, l.z); splitt(va.w, h.w, l.w);
      int sw = sw4(r, c4);
      *(ushort4*)&Ah[sw] = h; *(ushort4*)&Al[sw] = l;
      splitt(vb.x, h.x, l.x); splitt(vb.y, h.y, l.y);
      splitt(vb.z, h.z, l.z); splitt(vb.w, h.w, l.w);
      *(ushort4*)&Bh[sw] = h; *(ushort4*)&Bl[sw] = l;
    }
    __syncthreads();
#pragma unroll
    for (int ks = 0; ks < 2; ++ks) {
      bf16x8 ah[4], al[4], bh[4], bl[4];
#pragma unroll
      for (int i = 0; i < 4; ++i) {
        int ra = wm + (i << 4) + fr;
        int oa = (ra << 6) + ((((ks << 2) | fq) ^ (ra & 7)) << 3);
        ah[i] = *(const bf16x8*)&Ah[oa];
        al[i] = *(const bf16x8*)&Al[oa];
        int rb = wn + (i << 4) + fr;
        int ob = (rb << 6) + ((((ks << 2) | fq) ^ (rb & 7)) << 3);
        bh[i] = *(const bf16x8*)&Bh[ob];
        bl[i] = *(const bf16x8*)&Bl[ob];
      }
#pragma unroll
      for (int mt = 0; mt < 4; ++mt)
#pragma unroll
        for (int nt = 0; nt < 4; ++nt) {
          f32x4 c = acc[(mt << 2) + nt];
          c = __builtin_amdgcn_mfma_f32_16x16x32_bf16(ah[mt], bh[nt], c, 0, 0, 0);
          c = __builtin_amdgcn_mfma_f32_16x16x32_bf16(al[mt], bh[nt], c, 0, 0, 0);
          c = __builtin_amdgcn_mfma_f32_16x16x32_bf16(ah[mt], bl[nt], c, 0, 0, 0);
          acc[(mt << 2) + nt] = c;
        }
    }
  }
  float* C = attn + ((size_t)b * TDEC + t0) * TSRC + s0;
#pragma unroll
  for (int mt = 0; mt < 4; ++mt) {
    int r0 = wm + (mt << 4) + (fq << 2);
#pragma unroll
    for (int nt = 0; nt < 4; ++nt) {
      int c0 = wn + (nt << 4) + fr;
      f32x4 v = acc[(mt << 2) + nt];
#pragma unroll
      for (int j = 0; j < 4; ++j)
        C[(size_t)(r0 + j) * TSRC + c0] = v[j];
    }
  }
}

// ---------- kernel 5: masked softmax over rows (in place) + bf16 copy ----------
__global__ __launch_bounds__(256) void softmax_kernel(float* __restrict__ attn,
                                                      const int* __restrict__ lens,
                                                      unsigned short* __restrict__ attn_bf) {
  int b = blockIdx.y;
  int t = blockIdx.x;
  int len = lens[b];
  float* row = attn + ((size_t)b * TDEC + t) * TSRC;
  int tid = threadIdx.x;
  int p0 = tid << 2;
  int p1 = 1024 + (tid << 2);
  float4 v0 = *(const float4*)(row + p0);
  float4 v1 = *(const float4*)(row + p1);
  float x[8] = {v0.x, v0.y, v0.z, v0.w, v1.x, v1.y, v1.z, v1.w};
  float m = -3.4e38f;
#pragma unroll
  for (int j = 0; j < 8; ++j) {
    int pos = (j < 4) ? (p0 + j) : (p1 + j - 4);
    if (pos < len) m = fmaxf(m, x[j]);
  }
#pragma unroll
  for (int o = 32; o > 0; o >>= 1) m = fmaxf(m, __shfl_down(m, o, 64));
  __shared__ float redm[4], reds[4];
  if ((tid & 63) == 0) redm[tid >> 6] = m;
  __syncthreads();
  m = fmaxf(fmaxf(redm[0], redm[1]), fmaxf(redm[2], redm[3]));
  float e[8];
  float s = 0.f;
#pragma unroll
  for (int j = 0; j < 8; ++j) {
    int pos = (j < 4) ? (p0 + j) : (p1 + j - 4);
    float ev = (pos < len) ? __expf(x[j] - m) : 0.f;  // masked -> exact 0
    e[j] = ev;
    s += ev;
  }
#pragma unroll
  for (int o = 32; o > 0; o >>= 1) s += __shfl_down(s, o, 64);
  if ((tid & 63) == 0) reds[tid >> 6] = s;
  __syncthreads();
  s = reds[0] + reds[1] + reds[2] + reds[3];
  float inv = 1.0f / s;
  float4 o0, o1;
  o0.x = e[0] * inv; o0.y = e[1] * inv; o0.z = e[2] * inv; o0.w = e[3] * inv;
  o1.x = e[4] * inv; o1.y = e[5] * inv; o1.z = e[6] * inv; o1.w = e[7] * inv;
  *(float4*)(row + p0) = o0;
  *(float4*)(row + p1) = o1;
  if (attn_bf) {  // pointer constant across calls: graph-safe uniform branch
    unsigned short* rb = attn_bf + ((size_t)b * TDEC + t) * TSRC;
    ushort4 h0, h1;
    h0.x = f2bf(o0.x); h0.y = f2bf(o0.y); h0.z = f2bf(o0.z); h0.w = f2bf(o0.w);
    h1.x = f2bf(o1.x); h1.y = f2bf(o1.y); h1.z = f2bf(o1.z); h1.w = f2bf(o1.w);
    *(ushort4*)(rb + p0) = h0;
    *(ushort4*)(rb + p1) = h1;
  }
}

// ---------- kernel 6: context = attn_bf16 @ encT, 2-phase pipelined ----------
__global__ __launch_bounds__(256, 2) void context_pre(
    const unsigned short* __restrict__ attn_bf, const unsigned short* __restrict__ encT,
    float* __restrict__ ctx, const int* __restrict__ lens) {
  int b = blockIdx.z;
  int d0 = blockIdx.x << 7;
  int t0 = blockIdx.y << 7;
  int nk = (lens[b] + 63) >> 6;  // attn_bf is exactly 0 beyond len; nk >= 16
  __shared__ __align__(16) unsigned short As[2][8192], Bs[2][8192];  // 64 KB
  const unsigned short* Ag = attn_bf + ((size_t)b * TDEC + t0) * TSRC;
  const unsigned short* Bg = encT + ((size_t)b * DDIM + d0) * TSRC;
  int tid = threadIdx.x;
  int lane = tid & 63, wid = tid >> 6;
  int wm = (wid >> 1) << 6, wn = (wid & 1) << 6;
  int fr = lane & 15, fq = lane >> 4;

  int gg[4]; size_t go[4];
#pragma unroll
  for (int p = 0; p < 4; ++p) {
    int g = (p << 8) + tid;
    int r = g >> 3;
    int sg = (g & 7) ^ (r & 7);
    gg[p] = g << 3;
    go[p] = (size_t)r * TSRC + (sg << 3);
  }

  f32x4 acc[16];
#pragma unroll
  for (int i = 0; i < 16; ++i) { acc[i][0] = 0.f; acc[i][1] = 0.f; acc[i][2] = 0.f; acc[i][3] = 0.f; }

  auto stage = [&](int buf, int kc) {
    int k0 = kc << 6;
    unsigned short* Ad = &As[buf][0];
    unsigned short* Bd = &Bs[buf][0];
#pragma unroll
    for (int p = 0; p < 4; ++p) {
      gload16(Ag + go[p] + k0, Ad + gg[p]);
      gload16(Bg + go[p] + k0, Bd + gg[p]);
    }
  };

  auto compute = [&](int buf) {
    const unsigned short* At = &As[buf][0];
    const unsigned short* Bt = &Bs[buf][0];
#pragma unroll
    for (int ks = 0; ks < 2; ++ks) {
      bf16x8 a[4], bb[4];
#pragma unroll
      for (int i = 0; i < 4; ++i) {
        int ra = wm + (i << 4) + fr;
        a[i] = *(const bf16x8*)&At[(ra << 6) + ((((ks << 2) | fq) ^ (ra & 7)) << 3)];
        int rb = wn + (i << 4) + fr;
        bb[i] = *(const bf16x8*)&Bt[(rb << 6) + ((((ks << 2) | fq) ^ (rb & 7)) << 3)];
      }
#pragma unroll
      for (int mt = 0; mt < 4; ++mt)
#pragma unroll
        for (int nt = 0; nt < 4; ++nt)
          acc[(mt << 2) + nt] = __builtin_amdgcn_mfma_f32_16x16x32_bf16(
              a[mt], bb[nt], acc[(mt << 2) + nt], 0, 0, 0);
    }
  };

  stage(0, 0);
  int cur = 0;
  for (int kc = 0; kc < nk - 1; ++kc) {
    stage(cur ^ 1, kc + 1);
    asm volatile("s_waitcnt vmcnt(8)" ::: "memory");
    __builtin_amdgcn_s_barrier();
    __builtin_amdgcn_sched_barrier(0);
    compute(cur);
    __builtin_amdgcn_sched_barrier(0);
    __builtin_amdgcn_s_barrier();
    cur ^= 1;
  }
  asm volatile("s_waitcnt vmcnt(0)" ::: "memory");
  __builtin_amdgcn_s_barrier();
  __builtin_amdgcn_sched_barrier(0);
  compute(cur);

  float* C = ctx + ((size_t)b * TDEC + t0) * DDIM + d0;
#pragma unroll
  for (int mt = 0; mt < 4; ++mt) {
    int r0 = wm + (mt << 4) + (fq << 2);
#pragma unroll
    for (int nt = 0; nt < 4; ++nt) {
      int c0 = wn + (nt << 4) + fr;
      f32x4 v = acc[(mt << 2) + nt];
#pragma unroll
      for (int j = 0; j < 4; ++j)
        C[(size_t)(r0 + j) * DDIM + c0] = v[j];
    }
  }
}

// ---------- context fallback: B transposed in LDS from fp32 enc ----------
__global__ __launch_bounds__(256, 2) void context_fly(
    const float* __restrict__ attn, const float* __restrict__ enc,
    float* __restrict__ ctx, const int* __restrict__ lens) {
  int b = blockIdx.z;
  int d0 = blockIdx.x << 7;
  int t0 = blockIdx.y << 7;
  int nk = (lens[b] + 63) >> 6;
  __shared__ unsigned short At[8192], Bt[8192];
  const float* Ag = attn + ((size_t)b * TDEC + t0) * TSRC;
  const float* Bg = enc + (size_t)b * TSRC * DDIM + d0;
  int tid = threadIdx.x;
  int lane = tid & 63, wid = tid >> 6;
  int wm = (wid >> 1) << 6, wn = (wid & 1) << 6;
  int fr = lane & 15, fq = lane >> 4;

  f32x4 acc[16];
#pragma unroll
  for (int i = 0; i < 16; ++i) { acc[i][0] = 0.f; acc[i][1] = 0.f; acc[i][2] = 0.f; acc[i][3] = 0.f; }

  for (int kc = 0; kc < nk; ++kc) {
    int k0 = kc << 6;
    __syncthreads();
#pragma unroll
    for (int p = 0; p < 8; ++p) {
      int r = (p << 4) + (tid >> 4);
      int c4 = (tid & 15) << 2;
      float4 v = *(const float4*)(Ag + (size_t)r * TSRC + k0 + c4);
      ushort4 h;
      h.x = f2bf(v.x); h.y = f2bf(v.y); h.z = f2bf(v.z); h.w = f2bf(v.w);
      *(ushort4*)&At[sw4(r, c4)] = h;
    }
#pragma unroll
    for (int p = 0; p < 8; ++p) {  // B: enc[s][d] -> LDS [n=d][k=s]
      int idx = (p << 8) + tid;
      int sl = idx >> 5;
      int d4 = (idx & 31) << 2;
      float4 v = *(const float4*)(Bg + (size_t)(k0 + sl) * DDIM + d4);
      float tmp[4] = {v.x, v.y, v.z, v.w};
#pragma unroll
      for (int j = 0; j < 4; ++j) {
        int n = d4 + j;
        Bt[(n << 6) + ((((sl >> 3) ^ (n & 7)) << 3) | (sl & 7))] = f2bf(tmp[j]);
      }
    }
    __syncthreads();
#pragma unroll
    for (int ks = 0; ks < 2; ++ks) {
      bf16x8 a[4], bb[4];
#pragma unroll
      for (int i = 0; i < 4; ++i) {
        int ra = wm + (i << 4) + fr;
        a[i] = *(const bf16x8*)&At[(ra << 6) + ((((ks << 2) | fq) ^ (ra & 7)) << 3)];
        int rb = wn + (i << 4) + fr;
        bb[i] = *(const bf16x8*)&Bt[(rb << 6) + ((((ks << 2) | fq) ^ (rb & 7)) << 3)];
      }
#pragma unroll
      for (int mt = 0; mt < 4; ++mt)
#pragma unroll
        for (int nt = 0; nt < 4; ++nt)
          acc[(mt << 2) + nt] = __builtin_amdgcn_mfma_f32_16x16x32_bf16(
              a[mt], bb[nt], acc[(mt << 2) + nt], 0, 0, 0);
    }
  }
  float* C = ctx + ((size_t)b * TDEC + t0) * DDIM + d0;
#pragma unroll
  for (int mt = 0; mt < 4; ++mt) {
    int r0 = wm + (mt << 4) + (fq << 2);
#pragma unroll
    for (int nt = 0; nt < 4; ++nt) {
      int c0 = wn + (nt << 4) + fr;
      f32x4 v = acc[(mt << 2) + nt];
#pragma unroll
      for (int j = 0; j < 4; ++j)
        C[(size_t)(r0 + j) * DDIM + c0] = v[j];
    }
  }
}

// ---------- host ----------
extern "C" void kernel_launch(void* const* d_in, const int* in_sizes, int n_in,
                              void* d_out, int out_size, void* d_ws, size_t ws_size,
                              hipStream_t stream) {
  (void)in_sizes; (void)n_in; (void)out_size;
  const float* dec = (const float*)d_in[0];
  const float* enc = (const float*)d_in[1];
  const unsigned char* mask = (const unsigned char*)d_in[2];
  float* ctx = (float*)d_out;
  float* attn = ctx + (size_t)NB * TDEC * DDIM;

  size_t nDec = (size_t)NB * TDEC * DDIM;  // 33,554,432
  size_t nEnc = (size_t)NB * TSRC * DDIM;  // 67,108,864
  char* wsb = (char*)d_ws;
  int* lens = (int*)wsb;
  unsigned short* dec_hi = (unsigned short*)(wsb + 256);
  unsigned short* dec_lo = dec_hi + nDec;
  unsigned short* enc_hi = dec_lo + nDec;
  unsigned short* enc_lo = enc_hi + nEnc;
  unsigned short* encT = enc_lo + nEnc;
  // attn_bf16 (NB*TDEC*TSRC = 2*nDec ushorts) aliases dec_hi+dec_lo, which are
  // dead after scores_pre. Stream order: split -> scores (reads) -> softmax
  // (overwrites) -> context (reads). No extra workspace needed.
  unsigned short* attn_bf = dec_hi;
  size_t need = 256 + (2 * nDec + 3 * nEnc) * sizeof(unsigned short);  // ~512 MB
  int pre = (ws_size >= need) ? 1 : 0;  // constant across calls: graph-safe

  lens_kernel<<<NB, 256, 0, stream>>>(mask, lens);
  if (pre) {
    split_kernel<<<(int)(nDec / 4 / 256), 256, 0, stream>>>(dec, dec_hi, dec_lo, (int)(nDec / 4));
    encprep_kernel<<<dim3(TSRC / 64, DDIM / 64, NB), 256, 0, stream>>>(enc, enc_hi, enc_lo, encT);
    scores_pre<<<dim3(TSRC / 128, TDEC / 128, NB), 256, 0, stream>>>(
        dec_hi, dec_lo, enc_hi, enc_lo, attn, lens);
  } else {
    scores_fly<<<dim3(TSRC / 128, TDEC / 128, NB), 256, 0, stream>>>(dec, enc, attn, lens);
  }
  softmax_kernel<<<dim3(TDEC, NB), 256, 0, stream>>>(attn, lens, pre ? attn_bf : (unsigned short*)nullptr);
  if (pre) {
    context_pre<<<dim3(DDIM / 128, TDEC / 128, NB), 256, 0, stream>>>(attn_bf, encT, ctx, lens);
  } else {
    context_fly<<<dim3(DDIM / 128, TDEC / 128, NB), 256, 0, stream>>>(attn, enc, ctx, lens);
  }
}

// Round 7
// 1280.126 us; speedup vs baseline: 1.0145x; 1.0145x over previous
//
#include <hip/hip_runtime.h>
#include <stdint.h>

#define NB 32
#define TDEC 1024
#define TSRC 2048
#define DDIM 1024

typedef short bf16x8 __attribute__((ext_vector_type(8)));
typedef float f32x4 __attribute__((ext_vector_type(4)));

// ---------- helpers ----------

__device__ __forceinline__ unsigned short f2bf(float f) {  // round-to-nearest bf16
  union { float f; uint32_t u; } c; c.f = f;
  return (unsigned short)((c.u + 0x7FFFu + ((c.u >> 16) & 1u)) >> 16);
}

// truncating split: f = hi + lo (+ residual ~2^-17 |f|)
__device__ __forceinline__ void splitt(float f, unsigned short& h, unsigned short& l) {
  union { float f; uint32_t u; } c; c.f = f;
  uint32_t hb = c.u & 0xFFFF0000u;
  h = (unsigned short)(hb >> 16);
  union { uint32_t u; float f; } hf; hf.u = hb;
  union { float f; uint32_t u; } d; d.f = f - hf.f;
  l = (unsigned short)(d.u >> 16);
}

// XOR-swizzled LDS index for 128x64 bf16 tiles (row stride 64, granule = 8 bf16):
// slot s of row r holds global k-granule s^(r&7). 0 bank conflicts measured.
__device__ __forceinline__ int sw4(int r, int c4) {
  return (r << 6) + ((((c4 >> 3) ^ (r & 7)) << 3) | (c4 & 7));
}
__device__ __forceinline__ int sw8(int r, int c8) {
  return (r << 6) + (((c8 >> 3) ^ (r & 7)) << 3);
}

// async global->LDS, 16B per lane. LDS dest must be wave-uniform base + lane*16
// (linear); swizzle is applied by PRE-SWIZZLING the per-lane global source
// address (rule 21 / m173; XOR swizzle is its own inverse).
__device__ __forceinline__ void gload16(const void* g, void* l) {
  __builtin_amdgcn_global_load_lds(
      reinterpret_cast<const __attribute__((address_space(1))) uint32_t*>(
          reinterpret_cast<uintptr_t>(g)),
      reinterpret_cast<__attribute__((address_space(3))) uint32_t*>(
          reinterpret_cast<uintptr_t>(l)),
      16, 0, 0);
}

// ---------- kernel 1: mask -> per-batch valid length ----------
__global__ void lens_kernel(const unsigned char* __restrict__ mask,
                            int* __restrict__ lens) {
  int b = blockIdx.x;
  int tid = threadIdx.x;
  unsigned char b1 = mask[1], b3 = mask[3];
  int cnt = 0;
  if (b1 != 0) {
    const unsigned char* row = mask + (size_t)b * TSRC;
    for (int s = tid; s < TSRC; s += 256) cnt += (row[s] != 0) ? 1 : 0;
  } else if (b3 != 0) {
    const float* row = (const float*)mask + (size_t)b * TSRC;
    for (int s = tid; s < TSRC; s += 256) cnt += (row[s] != 0.0f) ? 1 : 0;
  } else {
    const int* row = (const int*)mask + (size_t)b * TSRC;
    for (int s = tid; s < TSRC; s += 256) cnt += (row[s] != 0) ? 1 : 0;
  }
#pragma unroll
  for (int o = 32; o > 0; o >>= 1) cnt += __shfl_down(cnt, o, 64);
  __shared__ int red[4];
  if ((tid & 63) == 0) red[tid >> 6] = cnt;
  __syncthreads();
  if (tid == 0) lens[b] = red[0] + red[1] + red[2] + red[3];
}

// ---------- kernel 2: dec fp32 -> bf16 hi/lo split (flat) ----------
__global__ void split_kernel(const float* __restrict__ src,
                             unsigned short* __restrict__ hi,
                             unsigned short* __restrict__ lo, int n4) {
  int i = blockIdx.x * 256 + threadIdx.x;
  if (i >= n4) return;
  float4 v = *(const float4*)(src + (size_t)i * 4);
  ushort4 h, l;
  splitt(v.x, h.x, l.x); splitt(v.y, h.y, l.y);
  splitt(v.z, h.z, l.z); splitt(v.w, h.w, l.w);
  *(ushort4*)(hi + (size_t)i * 4) = h;
  *(ushort4*)(lo + (size_t)i * 4) = l;
}

// ---------- kernel 3: enc -> {enc_hi, enc_lo} [s][d] + encT [d][s] in ONE read ----------
__global__ void encprep_kernel(const float* __restrict__ enc,
                               unsigned short* __restrict__ ehi,
                               unsigned short* __restrict__ elo,
                               unsigned short* __restrict__ encT) {
  __shared__ float tile[64][65];  // +1 pad: conflict-free both phases
  int b = blockIdx.z;
  int s0 = blockIdx.x << 6;
  int d0 = blockIdx.y << 6;
  int tid = threadIdx.x;
  int rl = tid >> 4;             // 0..15
  int c4 = (tid & 15) << 2;      // 0..60
  const float* src = enc + ((size_t)b * TSRC + s0) * DDIM + d0;
  unsigned short* hdst = ehi + ((size_t)b * TSRC + s0) * DDIM + d0;
  unsigned short* ldst = elo + ((size_t)b * TSRC + s0) * DDIM + d0;
#pragma unroll
  for (int p = 0; p < 4; ++p) {
    int s = rl + (p << 4);
    float4 v = *(const float4*)(src + (size_t)s * DDIM + c4);
    tile[s][c4 + 0] = v.x; tile[s][c4 + 1] = v.y;
    tile[s][c4 + 2] = v.z; tile[s][c4 + 3] = v.w;
    ushort4 h, l;
    splitt(v.x, h.x, l.x); splitt(v.y, h.y, l.y);
    splitt(v.z, h.z, l.z); splitt(v.w, h.w, l.w);
    *(ushort4*)(hdst + (size_t)s * DDIM + c4) = h;
    *(ushort4*)(ldst + (size_t)s * DDIM + c4) = l;
  }
  __syncthreads();
  unsigned short* dst = encT + ((size_t)b * DDIM + d0) * TSRC + s0;
#pragma unroll
  for (int p = 0; p < 4; ++p) {
    int d = rl + (p << 4);
    ushort4 o;
    o.x = f2bf(tile[c4 + 0][d]);
    o.y = f2bf(tile[c4 + 1][d]);
    o.z = f2bf(tile[c4 + 2][d]);
    o.w = f2bf(tile[c4 + 3][d]);
    *(ushort4*)(dst + (size_t)d * TSRC + c4) = o;
  }
}

// ---------- kernel 4: scores, 256x256 tile, BK=32, ring-4 LDS pipeline ----------
// concat-K (K'=96 subtiles of 32): seg0 dhi.ehi, seg1 dlo.ehi, seg2 dhi.elo.
// 512 thr = 8 waves (2M x 4N), per-wave 128x64 output, 32 MFMA/subtile.
// Ring of 4 slots per operand; stage(s+3) issued in block s; counted vmcnt(8)
// (= stages s+2,s+3 in flight) guarantees s+1 complete at the block-end
// barrier; WAR on slot (s-1)&3 covered by block s-1's end barrier.
#define SC_NSUB 96
__global__ __launch_bounds__(512, 1) void scores_pre(
    const unsigned short* __restrict__ dhi, const unsigned short* __restrict__ dlo,
    const unsigned short* __restrict__ ehi, const unsigned short* __restrict__ elo,
    float* __restrict__ attn, const int* __restrict__ lens) {
  // bijective XCD chunk swizzle: 1024 blocks = 8 XCDs x 128; each XCD gets a
  // batch-contiguous chunk -> same-XCD L2 panel reuse.
  int lid = blockIdx.x;
  int swz = ((lid & 7) << 7) + (lid >> 3);
  int sx = swz & 7, sy = (swz >> 3) & 3, b = swz >> 5;
  int s0 = sx << 8, t0 = sy << 8;
  if (s0 >= lens[b]) return;  // uniform per block: no barrier divergence
  __shared__ __align__(16) unsigned short As[4][8192], Bs[4][8192];  // 128 KB
  const unsigned short* Ah_ = dhi + ((size_t)b * TDEC + t0) * DDIM;
  const unsigned short* Al_ = dlo + ((size_t)b * TDEC + t0) * DDIM;
  const unsigned short* Bh_ = ehi + ((size_t)b * TSRC + s0) * DDIM;
  const unsigned short* Bl_ = elo + ((size_t)b * TSRC + s0) * DDIM;
  int tid = threadIdx.x;
  int lane = tid & 63, wid = tid >> 6;
  int wm = (wid >> 2) << 7;   // 0 / 128
  int wn = (wid & 3) << 6;    // 0 / 64 / 128 / 192
  int fr = lane & 15, fq = lane >> 4;

  // staging: subtile = 256 rows x 32 elems (4 granules/row). granule
  // g = q*512+tid; r=g>>2; slot=g&3; source granule sg = slot ^ ((r>>1)&3).
  int gg[2]; size_t go[2];
#pragma unroll
  for (int q = 0; q < 2; ++q) {
    int g = (q << 9) + tid;
    int r = g >> 2;
    int sg = (g & 3) ^ ((r >> 1) & 3);
    gg[q] = g << 3;                       // linear LDS elem offset
    go[q] = (size_t)r * DDIM + (sg << 3); // pre-swizzled global elem offset
  }

  f32x4 acc[8][4];
#pragma unroll
  for (int i = 0; i < 8; ++i)
#pragma unroll
    for (int n = 0; n < 4; ++n) { acc[i][n][0] = 0.f; acc[i][n][1] = 0.f; acc[i][n][2] = 0.f; acc[i][n][3] = 0.f; }

  auto stage = [&](int s) {
    const unsigned short* Asrc = (s >= 32 && s < 64) ? Al_ : Ah_;
    const unsigned short* Bsrc = (s >= 64) ? Bl_ : Bh_;
    int k0 = (s & 31) << 5;
    int slot = s & 3;
#pragma unroll
    for (int q = 0; q < 2; ++q) {
      gload16(Asrc + go[q] + k0, &As[slot][gg[q]]);
      gload16(Bsrc + go[q] + k0, &Bs[slot][gg[q]]);
    }
  };

  // prologue: 3 subtiles in flight, wait for subtile 0 (vmcnt 8 = subtiles 1,2)
  stage(0); stage(1); stage(2);
  asm volatile("s_waitcnt vmcnt(8)" ::: "memory");
  __builtin_amdgcn_s_barrier();

  for (int s = 0; s < SC_NSUB; ++s) {
    int slot = s & 3;
    const unsigned short* At = &As[slot][0];
    const unsigned short* Bt = &Bs[slot][0];
    bf16x8 bfr[4], afr[8];
#pragma unroll
    for (int n = 0; n < 4; ++n) {
      int rb = wn + (n << 4) + fr;
      bfr[n] = *(const bf16x8*)&Bt[(rb << 5) + ((fq ^ ((rb >> 1) & 3)) << 3)];
    }
#pragma unroll
    for (int i = 0; i < 4; ++i) {
      int ra = wm + (i << 4) + fr;
      afr[i] = *(const bf16x8*)&At[(ra << 5) + ((fq ^ ((ra >> 1) & 3)) << 3)];
    }
    if (s + 3 < SC_NSUB) stage(s + 3);  // writes slot (s-1)&3: safe post-barrier
    __builtin_amdgcn_s_setprio(1);
#pragma unroll
    for (int i = 0; i < 4; ++i)
#pragma unroll
      for (int n = 0; n < 4; ++n)
        acc[i][n] = __builtin_amdgcn_mfma_f32_16x16x32_bf16(afr[i], bfr[n], acc[i][n], 0, 0, 0);
    __builtin_amdgcn_s_setprio(0);
#pragma unroll
    for (int i = 4; i < 8; ++i) {
      int ra = wm + (i << 4) + fr;
      afr[i] = *(const bf16x8*)&At[(ra << 5) + ((fq ^ ((ra >> 1) & 3)) << 3)];
    }
    __builtin_amdgcn_s_setprio(1);
#pragma unroll
    for (int i = 4; i < 8; ++i)
#pragma unroll
      for (int n = 0; n < 4; ++n)
        acc[i][n] = __builtin_amdgcn_mfma_f32_16x16x32_bf16(afr[i], bfr[n], acc[i][n], 0, 0, 0);
    __builtin_amdgcn_s_setprio(0);
    // ensure subtile s+1 resident before next block's reads; keep s+2,s+3 in flight
    if (s < SC_NSUB - 3)       asm volatile("s_waitcnt vmcnt(8)" ::: "memory");
    else if (s == SC_NSUB - 3) asm volatile("s_waitcnt vmcnt(4)" ::: "memory");
    else if (s == SC_NSUB - 2) asm volatile("s_waitcnt vmcnt(0)" ::: "memory");
    if (s < SC_NSUB - 1) __builtin_amdgcn_s_barrier();
  }

  // C/D layout (verified m89): col = lane&15, row = (lane>>4)*4 + reg
  float* C = attn + ((size_t)b * TDEC + t0) * TSRC + s0;
#pragma unroll
  for (int i = 0; i < 8; ++i) {
    int r0 = wm + (i << 4) + (fq << 2);
#pragma unroll
    for (int n = 0; n < 4; ++n) {
      int c0 = wn + (n << 4) + fr;
      f32x4 v = acc[i][n];
#pragma unroll
      for (int j = 0; j < 4; ++j)
        C[(size_t)(r0 + j) * TSRC + c0] = v[j];
    }
  }
}

// ---------- scores fallback: on-the-fly split from fp32 (small-ws path) ----------
__global__ __launch_bounds__(256, 2) void scores_fly(
    const float* __restrict__ dec, const float* __restrict__ enc,
    float* __restrict__ attn, const int* __restrict__ lens) {
  int b = blockIdx.z;
  int s0 = blockIdx.x << 7;
  int t0 = blockIdx.y << 7;
  if (s0 >= lens[b]) return;
  __shared__ unsigned short Ah[8192], Al[8192], Bh[8192], Bl[8192];
  const float* Ag = dec + ((size_t)b * TDEC + t0) * DDIM;
  const float* Bg = enc + ((size_t)b * TSRC + s0) * DDIM;
  int tid = threadIdx.x;
  int lane = tid & 63, wid = tid >> 6;
  int wm = (wid >> 1) << 6, wn = (wid & 1) << 6;
  int fr = lane & 15, fq = lane >> 4;

  f32x4 acc[16];
#pragma unroll
  for (int i = 0; i < 16; ++i) { acc[i][0] = 0.f; acc[i][1] = 0.f; acc[i][2] = 0.f; acc[i][3] = 0.f; }

  for (int kc = 0; kc < 16; ++kc) {
    int k0 = kc << 6;
    __syncthreads();
#pragma unroll
    for (int p = 0; p < 8; ++p) {
      int r = (p << 4) + (tid >> 4);
      int c4 = (tid & 15) << 2;
      size_t go = (size_t)r * DDIM + k0 + c4;
      float4 va = *(const float4*)(Ag + go);
      float4 vb = *(const float4*)(Bg + go);
      ushort4 h, l;
      splitt(va.x, h.x, l.x); splitt(va.y, h.y, l.y);
      splitt(va.z, h.z, l.z); splitt(va.w, h.w, l.w);
      int sw = sw4(r, c4);
      *(ushort4*)&Ah[sw] = h; *(ushort4*)&Al[sw] = l;
      splitt(vb.x, h.x, l.x); splitt(vb.y, h.y, l.y);
      splitt(vb.z, h.z, l.z); splitt(vb.w, h.w, l.w);
      *(ushort4*)&Bh[sw] = h; *(ushort4*)&Bl[sw] = l;
    }
    __syncthreads();
#pragma unroll
    for (int ks = 0; ks < 2; ++ks) {
      bf16x8 ah[4], al[4], bh[4], bl[4];
#pragma unroll
      for (int i = 0; i < 4; ++i) {
        int ra = wm + (i << 4) + fr;
        int oa = (ra << 6) + ((((ks << 2) | fq) ^ (ra & 7)) << 3);
        ah[i] = *(const bf16x8*)&Ah[oa];
        al[i] = *(const bf16x8*)&Al[oa];
        int rb = wn + (i << 4) + fr;
        int ob = (rb << 6) + ((((ks << 2) | fq) ^ (rb & 7)) << 3);
        bh[i] = *(const bf16x8*)&Bh[ob];
        bl[i] = *(const bf16x8*)&Bl[ob];
      }
#pragma unroll
      for (int mt = 0; mt < 4; ++mt)
#pragma unroll
        for (int nt = 0; nt < 4; ++nt) {
          f32x4 c = acc[(mt << 2) + nt];
          c = __builtin_amdgcn_mfma_f32_16x16x32_bf16(ah[mt], bh[nt], c, 0, 0, 0);
          c = __builtin_amdgcn_mfma_f32_16x16x32_bf16(al[mt], bh[nt], c, 0, 0, 0);
          c = __builtin_amdgcn_mfma_f32_16x16x32_bf16(ah[mt], bl[nt], c, 0, 0, 0);
          acc[(mt << 2) + nt] = c;
        }
    }
  }
  float* C = attn + ((size_t)b * TDEC + t0) * TSRC + s0;
#pragma unroll
  for (int mt = 0; mt < 4; ++mt) {
    int r0 = wm + (mt << 4) + (fq << 2);
#pragma unroll
    for (int nt = 0; nt < 4; ++nt) {
      int c0 = wn + (nt << 4) + fr;
      f32x4 v = acc[(mt << 2) + nt];
#pragma unroll
      for (int j = 0; j < 4; ++j)
        C[(size_t)(r0 + j) * TSRC + c0] = v[j];
    }
  }
}

// ---------- kernel 5: masked softmax over rows (in place) + bf16 copy ----------
__global__ __launch_bounds__(256) void softmax_kernel(float* __restrict__ attn,
                                                      const int* __restrict__ lens,
                                                      unsigned short* __restrict__ attn_bf) {
  int b = blockIdx.y;
  int t = blockIdx.x;
  int len = lens[b];
  float* row = attn + ((size_t)b * TDEC + t) * TSRC;
  int tid = threadIdx.x;
  int p0 = tid << 2;
  int p1 = 1024 + (tid << 2);
  float4 v0 = *(const float4*)(row + p0);
  float4 v1 = *(const float4*)(row + p1);
  float x[8] = {v0.x, v0.y, v0.z, v0.w, v1.x, v1.y, v1.z, v1.w};
  float m = -3.4e38f;
#pragma unroll
  for (int j = 0; j < 8; ++j) {
    int pos = (j < 4) ? (p0 + j) : (p1 + j - 4);
    if (pos < len) m = fmaxf(m, x[j]);
  }
#pragma unroll
  for (int o = 32; o > 0; o >>= 1) m = fmaxf(m, __shfl_down(m, o, 64));
  __shared__ float redm[4], reds[4];
  if ((tid & 63) == 0) redm[tid >> 6] = m;
  __syncthreads();
  m = fmaxf(fmaxf(redm[0], redm[1]), fmaxf(redm[2], redm[3]));
  float e[8];
  float s = 0.f;
#pragma unroll
  for (int j = 0; j < 8; ++j) {
    int pos = (j < 4) ? (p0 + j) : (p1 + j - 4);
    float ev = (pos < len) ? __expf(x[j] - m) : 0.f;  // masked -> exact 0
    e[j] = ev;
    s += ev;
  }
#pragma unroll
  for (int o = 32; o > 0; o >>= 1) s += __shfl_down(s, o, 64);
  if ((tid & 63) == 0) reds[tid >> 6] = s;
  __syncthreads();
  s = reds[0] + reds[1] + reds[2] + reds[3];
  float inv = 1.0f / s;
  float4 o0, o1;
  o0.x = e[0] * inv; o0.y = e[1] * inv; o0.z = e[2] * inv; o0.w = e[3] * inv;
  o1.x = e[4] * inv; o1.y = e[5] * inv; o1.z = e[6] * inv; o1.w = e[7] * inv;
  *(float4*)(row + p0) = o0;
  *(float4*)(row + p1) = o1;
  if (attn_bf) {  // pointer constant across calls: graph-safe uniform branch
    unsigned short* rb = attn_bf + ((size_t)b * TDEC + t) * TSRC;
    ushort4 h0, h1;
    h0.x = f2bf(o0.x); h0.y = f2bf(o0.y); h0.z = f2bf(o0.z); h0.w = f2bf(o0.w);
    h1.x = f2bf(o1.x); h1.y = f2bf(o1.y); h1.z = f2bf(o1.z); h1.w = f2bf(o1.w);
    *(ushort4*)(rb + p0) = h0;
    *(ushort4*)(rb + p1) = h1;
  }
}

// ---------- kernel 6: context = attn_bf16 @ encT, 2-phase pipelined ----------
__global__ __launch_bounds__(256, 2) void context_pre(
    const unsigned short* __restrict__ attn_bf, const unsigned short* __restrict__ encT,
    float* __restrict__ ctx, const int* __restrict__ lens) {
  int b = blockIdx.z;
  int d0 = blockIdx.x << 7;
  int t0 = blockIdx.y << 7;
  int nk = (lens[b] + 63) >> 6;  // attn_bf is exactly 0 beyond len; nk >= 16
  __shared__ __align__(16) unsigned short As[2][8192], Bs[2][8192];  // 64 KB
  const unsigned short* Ag = attn_bf + ((size_t)b * TDEC + t0) * TSRC;
  const unsigned short* Bg = encT + ((size_t)b * DDIM + d0) * TSRC;
  int tid = threadIdx.x;
  int lane = tid & 63, wid = tid >> 6;
  int wm = (wid >> 1) << 6, wn = (wid & 1) << 6;
  int fr = lane & 15, fq = lane >> 4;

  int gg[4]; size_t go[4];
#pragma unroll
  for (int p = 0; p < 4; ++p) {
    int g = (p << 8) + tid;
    int r = g >> 3;
    int sg = (g & 7) ^ (r & 7);
    gg[p] = g << 3;
    go[p] = (size_t)r * TSRC + (sg << 3);
  }

  f32x4 acc[16];
#pragma unroll
  for (int i = 0; i < 16; ++i) { acc[i][0] = 0.f; acc[i][1] = 0.f; acc[i][2] = 0.f; acc[i][3] = 0.f; }

  auto stage = [&](int buf, int kc) {
    int k0 = kc << 6;
    unsigned short* Ad = &As[buf][0];
    unsigned short* Bd = &Bs[buf][0];
#pragma unroll
    for (int p = 0; p < 4; ++p) {
      gload16(Ag + go[p] + k0, Ad + gg[p]);
      gload16(Bg + go[p] + k0, Bd + gg[p]);
    }
  };

  auto compute = [&](int buf) {
    const unsigned short* At = &As[buf][0];
    const unsigned short* Bt = &Bs[buf][0];
#pragma unroll
    for (int ks = 0; ks < 2; ++ks) {
      bf16x8 a[4], bb[4];
#pragma unroll
      for (int i = 0; i < 4; ++i) {
        int ra = wm + (i << 4) + fr;
        a[i] = *(const bf16x8*)&At[(ra << 6) + ((((ks << 2) | fq) ^ (ra & 7)) << 3)];
        int rb = wn + (i << 4) + fr;
        bb[i] = *(const bf16x8*)&Bt[(rb << 6) + ((((ks << 2) | fq) ^ (rb & 7)) << 3)];
      }
#pragma unroll
      for (int mt = 0; mt < 4; ++mt)
#pragma unroll
        for (int nt = 0; nt < 4; ++nt)
          acc[(mt << 2) + nt] = __builtin_amdgcn_mfma_f32_16x16x32_bf16(
              a[mt], bb[nt], acc[(mt << 2) + nt], 0, 0, 0);
    }
  };

  stage(0, 0);
  int cur = 0;
  for (int kc = 0; kc < nk - 1; ++kc) {
    stage(cur ^ 1, kc + 1);
    asm volatile("s_waitcnt vmcnt(8)" ::: "memory");
    __builtin_amdgcn_s_barrier();
    __builtin_amdgcn_sched_barrier(0);
    compute(cur);
    __builtin_amdgcn_sched_barrier(0);
    __builtin_amdgcn_s_barrier();
    cur ^= 1;
  }
  asm volatile("s_waitcnt vmcnt(0)" ::: "memory");
  __builtin_amdgcn_s_barrier();
  __builtin_amdgcn_sched_barrier(0);
  compute(cur);

  float* C = ctx + ((size_t)b * TDEC + t0) * DDIM + d0;
#pragma unroll
  for (int mt = 0; mt < 4; ++mt) {
    int r0 = wm + (mt << 4) + (fq << 2);
#pragma unroll
    for (int nt = 0; nt < 4; ++nt) {
      int c0 = wn + (nt << 4) + fr;
      f32x4 v = acc[(mt << 2) + nt];
#pragma unroll
      for (int j = 0; j < 4; ++j)
        C[(size_t)(r0 + j) * DDIM + c0] = v[j];
    }
  }
}

// ---------- context fallback: B transposed in LDS from fp32 enc ----------
__global__ __launch_bounds__(256, 2) void context_fly(
    const float* __restrict__ attn, const float* __restrict__ enc,
    float* __restrict__ ctx, const int* __restrict__ lens) {
  int b = blockIdx.z;
  int d0 = blockIdx.x << 7;
  int t0 = blockIdx.y << 7;
  int nk = (lens[b] + 63) >> 6;
  __shared__ unsigned short At[8192], Bt[8192];
  const float* Ag = attn + ((size_t)b * TDEC + t0) * TSRC;
  const float* Bg = enc + (size_t)b * TSRC * DDIM + d0;
  int tid = threadIdx.x;
  int lane = tid & 63, wid = tid >> 6;
  int wm = (wid >> 1) << 6, wn = (wid & 1) << 6;
  int fr = lane & 15, fq = lane >> 4;

  f32x4 acc[16];
#pragma unroll
  for (int i = 0; i < 16; ++i) { acc[i][0] = 0.f; acc[i][1] = 0.f; acc[i][2] = 0.f; acc[i][3] = 0.f; }

  for (int kc = 0; kc < nk; ++kc) {
    int k0 = kc << 6;
    __syncthreads();
#pragma unroll
    for (int p = 0; p < 8; ++p) {
      int r = (p << 4) + (tid >> 4);
      int c4 = (tid & 15) << 2;
      float4 v = *(const float4*)(Ag + (size_t)r * TSRC + k0 + c4);
      ushort4 h;
      h.x = f2bf(v.x); h.y = f2bf(v.y); h.z = f2bf(v.z); h.w = f2bf(v.w);
      *(ushort4*)&At[sw4(r, c4)] = h;
    }
#pragma unroll
    for (int p = 0; p < 8; ++p) {  // B: enc[s][d] -> LDS [n=d][k=s]
      int idx = (p << 8) + tid;
      int sl = idx >> 5;
      int d4 = (idx & 31) << 2;
      float4 v = *(const float4*)(Bg + (size_t)(k0 + sl) * DDIM + d4);
      float tmp[4] = {v.x, v.y, v.z, v.w};
#pragma unroll
      for (int j = 0; j < 4; ++j) {
        int n = d4 + j;
        Bt[(n << 6) + ((((sl >> 3) ^ (n & 7)) << 3) | (sl & 7))] = f2bf(tmp[j]);
      }
    }
    __syncthreads();
#pragma unroll
    for (int ks = 0; ks < 2; ++ks) {
      bf16x8 a[4], bb[4];
#pragma unroll
      for (int i = 0; i < 4; ++i) {
        int ra = wm + (i << 4) + fr;
        a[i] = *(const bf16x8*)&At[(ra << 6) + ((((ks << 2) | fq) ^ (ra & 7)) << 3)];
        int rb = wn + (i << 4) + fr;
        bb[i] = *(const bf16x8*)&Bt[(rb << 6) + ((((ks << 2) | fq) ^ (rb & 7)) << 3)];
      }
#pragma unroll
      for (int mt = 0; mt < 4; ++mt)
#pragma unroll
        for (int nt = 0; nt < 4; ++nt)
          acc[(mt << 2) + nt] = __builtin_amdgcn_mfma_f32_16x16x32_bf16(
              a[mt], bb[nt], acc[(mt << 2) + nt], 0, 0, 0);
    }
  }
  float* C = ctx + ((size_t)b * TDEC + t0) * DDIM + d0;
#pragma unroll
  for (int mt = 0; mt < 4; ++mt) {
    int r0 = wm + (mt << 4) + (fq << 2);
#pragma unroll
    for (int nt = 0; nt < 4; ++nt) {
      int c0 = wn + (nt << 4) + fr;
      f32x4 v = acc[(mt << 2) + nt];
#pragma unroll
      for (int j = 0; j < 4; ++j)
        C[(size_t)(r0 + j) * DDIM + c0] = v[j];
    }
  }
}

// ---------- host ----------
extern "C" void kernel_launch(void* const* d_in, const int* in_sizes, int n_in,
                              void* d_out, int out_size, void* d_ws, size_t ws_size,
                              hipStream_t stream) {
  (void)in_sizes; (void)n_in; (void)out_size;
  const float* dec = (const float*)d_in[0];
  const float* enc = (const float*)d_in[1];
  const unsigned char* mask = (const unsigned char*)d_in[2];
  float* ctx = (float*)d_out;
  float* attn = ctx + (size_t)NB * TDEC * DDIM;

  size_t nDec = (size_t)NB * TDEC * DDIM;  // 33,554,432
  size_t nEnc = (size_t)NB * TSRC * DDIM;  // 67,108,864
  char* wsb = (char*)d_ws;
  int* lens = (int*)wsb;
  unsigned short* dec_hi = (unsigned short*)(wsb + 256);
  unsigned short* dec_lo = dec_hi + nDec;
  unsigned short* enc_hi = dec_lo + nDec;
  unsigned short* enc_lo = enc_hi + nEnc;
  unsigned short* encT = enc_lo + nEnc;
  // attn_bf16 (NB*TDEC*TSRC = 2*nDec ushorts) aliases dec_hi+dec_lo, which are
  // dead after scores_pre. Stream order: split -> scores (reads) -> softmax
  // (overwrites) -> context (reads). No extra workspace needed.
  unsigned short* attn_bf = dec_hi;
  size_t need = 256 + (2 * nDec + 3 * nEnc) * sizeof(unsigned short);  // ~512 MB
  int pre = (ws_size >= need) ? 1 : 0;  // constant across calls: graph-safe

  lens_kernel<<<NB, 256, 0, stream>>>(mask, lens);
  if (pre) {
    split_kernel<<<(int)(nDec / 4 / 256), 256, 0, stream>>>(dec, dec_hi, dec_lo, (int)(nDec / 4));
    encprep_kernel<<<dim3(TSRC / 64, DDIM / 64, NB), 256, 0, stream>>>(enc, enc_hi, enc_lo, encT);
    scores_pre<<<dim3((TSRC / 256) * (TDEC / 256) * NB), 512, 0, stream>>>(
        dec_hi, dec_lo, enc_hi, enc_lo, attn, lens);
  } else {
    scores_fly<<<dim3(TSRC / 128, TDEC / 128, NB), 256, 0, stream>>>(dec, enc, attn, lens);
  }
  softmax_kernel<<<dim3(TDEC, NB), 256, 0, stream>>>(attn, lens, pre ? attn_bf : (unsigned short*)nullptr);
  if (pre) {
    context_pre<<<dim3(DDIM / 128, TDEC / 128, NB), 256, 0, stream>>>(attn_bf, encT, ctx, lens);
  } else {
    context_fly<<<dim3(DDIM / 128, TDEC / 128, NB), 256, 0, stream>>>(attn, enc, ctx, lens);
  }
}